// Round 1
// baseline (238.538 us; speedup 1.0000x reference)
//
#include <hip/hip_runtime.h>

#define NROWS 8192
#define DDIM 64
#define MARGIN_F 1.0f
#define EPS_F 1e-6f
#define TM 64
#define TN 64

// ws layout (floats):
//  a2   [0, 8192)
//  p2   [8192, 16384)
//  pd1  [16384, 24576)   pos_dist + MARGIN
//  sel  [24576, 32768)   (int) compacted indices of labels==1
//  cnt  at 32768         (int)
//  total at 32769        (float)

__global__ void prep_kernel(const float* __restrict__ A, const float* __restrict__ P,
                            const int* __restrict__ labels,
                            float* __restrict__ a2, float* __restrict__ p2,
                            float* __restrict__ pd1, int* __restrict__ sel,
                            int* __restrict__ cnt) {
    int gid  = blockIdx.x * blockDim.x + threadIdx.x;
    int row  = gid >> 6;
    int lane = threadIdx.x & 63;
    if (row >= NROWS) return;
    float av = A[row * DDIM + lane] + EPS_F;
    float pv = P[row * DDIM + lane];
    float va2 = av * av;
    float vp2 = pv * pv;
    float vap = av * pv;
    #pragma unroll
    for (int off = 32; off; off >>= 1) {
        va2 += __shfl_xor(va2, off);
        vp2 += __shfl_xor(vp2, off);
        vap += __shfl_xor(vap, off);
    }
    if (lane == 0) {
        a2[row] = va2;
        p2[row] = vp2;
        float sq = fmaxf(va2 + vp2 - 2.0f * vap, 1e-12f);
        pd1[row] = sqrtf(sq) + MARGIN_F;
        if (labels[row] == 1) {
            int m = atomicAdd(cnt, 1);
            sel[m] = row;
        }
    }
}

__global__ __launch_bounds__(256) void
main_kernel(const float* __restrict__ A, const float* __restrict__ P,
            const float* __restrict__ a2, const float* __restrict__ p2,
            const float* __restrict__ pd1, const int* __restrict__ sel,
            const int* __restrict__ cnt, float* __restrict__ total) {
    __shared__ float As[DDIM][TM];   // k-major: As[k][row]
    __shared__ float Ps[DDIM][TN];   // k-major: Ps[k][col]
    __shared__ float sA2[TM], sPd[TM], sP2[TN];
    __shared__ int   sGi[TM];
    __shared__ float wsum[4];

    int M = *cnt;
    int row0 = blockIdx.y * TM;   // position in compacted selected-row list
    int col0 = blockIdx.x * TN;   // global positive index
    if (row0 >= M) return;        // uniform early-exit (labels==0 rows skipped)

    int t = threadIdx.x;

    // Stage per-row/col metadata
    if (t < TM) {
        int gi = sel[min(row0 + t, M - 1)];
        sGi[t] = gi;
        sA2[t] = a2[gi];
        sPd[t] = pd1[gi];
        sP2[t] = p2[col0 + t];
    }

    // Stage tiles, transposing to k-major. 64 rows x 16 float4 chunks each.
    const float4* A4 = (const float4*)A;
    const float4* P4 = (const float4*)P;
    #pragma unroll
    for (int it = 0; it < 4; ++it) {
        int c   = t + it * 256;
        int row = c >> 4;
        int kc  = c & 15;
        int gi  = sel[min(row0 + row, M - 1)];
        float4 ga = A4[gi * 16 + kc];
        As[kc * 4 + 0][row] = ga.x + EPS_F;
        As[kc * 4 + 1][row] = ga.y + EPS_F;
        As[kc * 4 + 2][row] = ga.z + EPS_F;
        As[kc * 4 + 3][row] = ga.w + EPS_F;
        float4 gp = P4[(col0 + row) * 16 + kc];
        Ps[kc * 4 + 0][row] = gp.x;
        Ps[kc * 4 + 1][row] = gp.y;
        Ps[kc * 4 + 2][row] = gp.z;
        Ps[kc * 4 + 3][row] = gp.w;
    }
    __syncthreads();

    int tc = t & 15;          // col group
    int tr = t >> 4;          // row group (0..15)

    float acc[4][4] = {};
    #pragma unroll
    for (int k = 0; k < DDIM; ++k) {
        float4 af = *(const float4*)&As[k][tr * 4];
        float4 pf = *(const float4*)&Ps[k][tc * 4];
        acc[0][0] += af.x * pf.x; acc[0][1] += af.x * pf.y; acc[0][2] += af.x * pf.z; acc[0][3] += af.x * pf.w;
        acc[1][0] += af.y * pf.x; acc[1][1] += af.y * pf.y; acc[1][2] += af.y * pf.z; acc[1][3] += af.y * pf.w;
        acc[2][0] += af.z * pf.x; acc[2][1] += af.z * pf.y; acc[2][2] += af.z * pf.z; acc[2][3] += af.z * pf.w;
        acc[3][0] += af.w * pf.x; acc[3][1] += af.w * pf.y; acc[3][2] += af.w * pf.z; acc[3][3] += af.w * pf.w;
    }

    // Fused epilogue: dist -> hinge -> masked accumulate
    float bsum = 0.0f;
    #pragma unroll
    for (int q = 0; q < 4; ++q) {
        int rr = tr * 4 + q;
        bool rvalid = (row0 + rr) < M;
        float ra2 = sA2[rr];
        float rpd = sPd[rr];
        int   gi  = sGi[rr];
        #pragma unroll
        for (int r = 0; r < 4; ++r) {
            int cc = tc * 4 + r;
            int j  = col0 + cc;
            float sq = fmaxf(ra2 + sP2[cc] - 2.0f * acc[q][r], 1e-12f);
            float h  = rpd - sqrtf(sq);
            if (rvalid && (gi != j) && (h > 0.0f)) bsum += h;
        }
    }

    // Block reduction -> one atomic
    #pragma unroll
    for (int off = 32; off; off >>= 1) bsum += __shfl_xor(bsum, off);
    int wid = t >> 6;
    if ((t & 63) == 0) wsum[wid] = bsum;
    __syncthreads();
    if (t == 0) atomicAdd(total, wsum[0] + wsum[1] + wsum[2] + wsum[3]);
}

__global__ void finalize_kernel(const int* __restrict__ cnt,
                                const float* __restrict__ total,
                                float* __restrict__ out) {
    int M = *cnt;
    float c = (float)M * (float)(NROWS - 1);
    out[0] = (M > 0) ? (*total) / c : 0.0f;
}

extern "C" void kernel_launch(void* const* d_in, const int* in_sizes, int n_in,
                              void* d_out, int out_size, void* d_ws, size_t ws_size,
                              hipStream_t stream) {
    const float* A      = (const float*)d_in[0];
    const float* P      = (const float*)d_in[1];
    const int*   labels = (const int*)d_in[2];
    float* out = (float*)d_out;

    float* wsf   = (float*)d_ws;
    float* a2    = wsf;
    float* p2    = wsf + 8192;
    float* pd1   = wsf + 16384;
    int*   sel   = (int*)(wsf + 24576);
    int*   cnt   = (int*)(wsf + 32768);
    float* total = wsf + 32769;

    // zero cnt (int) + total (float) — adjacent 8 bytes
    hipMemsetAsync((void*)cnt, 0, 8, stream);

    prep_kernel<<<dim3(NROWS / 4), dim3(256), 0, stream>>>(A, P, labels, a2, p2, pd1, sel, cnt);

    dim3 grid(NROWS / TN, NROWS / TM);
    main_kernel<<<grid, dim3(256), 0, stream>>>(A, P, a2, p2, pd1, sel, cnt, total);

    finalize_kernel<<<1, 1, 0, stream>>>(cnt, total, out);
}

// Round 2
// 147.636 us; speedup vs baseline: 1.6157x; 1.6157x over previous
//
#include <hip/hip_runtime.h>
#include <hip/hip_bf16.h>

#define NROWS 8192
#define DDIM 64
#define MARGIN_F 1.0f
#define EPS_F 1e-6f

// ws layout (bytes):
//  Abf   [0, 1048576)            bf16[8192][64]  compacted (a+eps) rows
//  Pbf   [1048576, 2097152)      bf16[8192][64]
//  a2c   [2097152, 2129920)      float[8192]     compacted |a+eps|^2
//  pdc   [2129920, 2162688)      float[8192]     compacted pos_dist+margin
//  p2g   [2162688, 2195456)      float[8192]     |p|^2 by global row
//  gic   [2195456, 2228224)      int[8192]       compacted -> global row idx
//  cnt   at 2228224 (int)
//  total at 2228228 (float)

typedef __attribute__((ext_vector_type(8))) short bf16x8;
typedef __attribute__((ext_vector_type(4))) float f32x4;

__global__ __launch_bounds__(256) void
prep_kernel(const float* __restrict__ A, const float* __restrict__ P,
            const int* __restrict__ labels,
            __hip_bfloat16* __restrict__ Abf, __hip_bfloat16* __restrict__ Pbf,
            float* __restrict__ a2c, float* __restrict__ pdc,
            float* __restrict__ p2g, int* __restrict__ gic,
            int* __restrict__ cnt) {
    int row  = blockIdx.x * 4 + (threadIdx.x >> 6);
    int lane = threadIdx.x & 63;
    float av = A[row * DDIM + lane] + EPS_F;
    float pv = P[row * DDIM + lane];
    Pbf[row * DDIM + lane] = __float2bfloat16(pv);
    float va2 = av * av;
    float vp2 = pv * pv;
    float vap = av * pv;
    #pragma unroll
    for (int off = 32; off; off >>= 1) {
        va2 += __shfl_xor(va2, off);
        vp2 += __shfl_xor(vp2, off);
        vap += __shfl_xor(vap, off);
    }
    if (lane == 0) p2g[row] = vp2;
    if (labels[row] == 1) {          // wave-uniform branch
        int m = 0;
        if (lane == 0) m = atomicAdd(cnt, 1);
        m = __shfl(m, 0);
        Abf[m * DDIM + lane] = __float2bfloat16(av);
        if (lane == 0) {
            a2c[m] = va2;
            float sq = fmaxf(va2 + vp2 - 2.0f * vap, 1e-12f);
            pdc[m] = sqrtf(sq) + MARGIN_F;
            gic[m] = row;
        }
    }
}

#define LDS_STRIDE 72   // bf16 elements per row (144 B): 2-way bank aliasing only

__global__ __launch_bounds__(256) void
main_kernel(const __hip_bfloat16* __restrict__ Abf, const __hip_bfloat16* __restrict__ Pbf,
            const float* __restrict__ a2c, const float* __restrict__ pdc,
            const float* __restrict__ p2g, const int* __restrict__ gic,
            const int* __restrict__ cnt, float* __restrict__ total) {
    __shared__ __align__(16) unsigned short As[128 * LDS_STRIDE];
    __shared__ __align__(16) unsigned short Ps2[128 * LDS_STRIDE];
    __shared__ float sA2[128], sPd[128], sP2[128];
    __shared__ int   sGi[128];
    __shared__ float wsum[4];

    int M = *cnt;
    int row0 = blockIdx.y * 128;   // position in compacted list
    int col0 = blockIdx.x * 128;   // global positive index
    if (row0 >= M) return;

    int t = threadIdx.x;

    if (t < 128) {
        int ri = min(row0 + t, M - 1);
        sA2[t] = a2c[ri];
        sPd[t] = pdc[ri];
        sGi[t] = gic[ri];
        sP2[t] = p2g[col0 + t];
    }

    // Stage tiles: 128 rows x 64 bf16 (8 chunks of 16B per row), padded stride.
    const float4* Asrc = (const float4*)Abf;
    const float4* Psrc = (const float4*)Pbf;
    #pragma unroll
    for (int i = 0; i < 4; ++i) {
        int c  = t + i * 256;      // 0..1023
        int r  = c >> 3;
        int kc = c & 7;
        int ar = min(row0 + r, M - 1);
        *(float4*)&As[r * LDS_STRIDE + kc * 8]  = Asrc[ar * 8 + kc];
        *(float4*)&Ps2[r * LDS_STRIDE + kc * 8] = Psrc[(col0 + r) * 8 + kc];
    }
    __syncthreads();

    int wid  = t >> 6;
    int lane = t & 63;
    int wm = (wid >> 1) * 64;      // wave's 64x64 sub-tile
    int wn = (wid & 1) * 64;
    int lm   = lane & 15;
    int quad = lane >> 4;

    f32x4 acc[4][4] = {};
    #pragma unroll
    for (int s = 0; s < 2; ++s) {
        bf16x8 af[4], bfr[4];
        #pragma unroll
        for (int a = 0; a < 4; ++a)
            af[a] = *(const bf16x8*)&As[(wm + a * 16 + lm) * LDS_STRIDE + s * 32 + quad * 8];
        #pragma unroll
        for (int b = 0; b < 4; ++b)
            bfr[b] = *(const bf16x8*)&Ps2[(wn + b * 16 + lm) * LDS_STRIDE + s * 32 + quad * 8];
        #pragma unroll
        for (int a = 0; a < 4; ++a)
            #pragma unroll
            for (int b = 0; b < 4; ++b)
                acc[a][b] = __builtin_amdgcn_mfma_f32_16x16x32_bf16(af[a], bfr[b], acc[a][b], 0, 0, 0);
    }

    // Fused epilogue. C/D layout: col = lane&15, row = quad*4 + reg.
    float bsum = 0.0f;
    #pragma unroll
    for (int a = 0; a < 4; ++a) {
        #pragma unroll
        for (int r = 0; r < 4; ++r) {
            int il = wm + a * 16 + quad * 4 + r;
            bool valid = (row0 + il) < M;
            float ra2 = sA2[il];
            float rpd = sPd[il];
            int   gi  = sGi[il];
            #pragma unroll
            for (int b = 0; b < 4; ++b) {
                int jl = wn + b * 16 + lm;
                int j  = col0 + jl;
                float sq = fmaxf(ra2 + sP2[jl] - 2.0f * acc[a][b][r], 1e-12f);
                float h  = rpd - sqrtf(sq);
                if (valid && (gi != j) && (h > 0.0f)) bsum += h;
            }
        }
    }

    #pragma unroll
    for (int off = 32; off; off >>= 1) bsum += __shfl_xor(bsum, off);
    if (lane == 0) wsum[wid] = bsum;
    __syncthreads();
    if (t == 0) atomicAdd(total, wsum[0] + wsum[1] + wsum[2] + wsum[3]);
}

__global__ void finalize_kernel(const int* __restrict__ cnt,
                                const float* __restrict__ total,
                                float* __restrict__ out) {
    int M = *cnt;
    float c = (float)M * (float)(NROWS - 1);
    out[0] = (M > 0) ? (*total) / c : 0.0f;
}

extern "C" void kernel_launch(void* const* d_in, const int* in_sizes, int n_in,
                              void* d_out, int out_size, void* d_ws, size_t ws_size,
                              hipStream_t stream) {
    const float* A      = (const float*)d_in[0];
    const float* P      = (const float*)d_in[1];
    const int*   labels = (const int*)d_in[2];
    float* out = (float*)d_out;

    char* ws = (char*)d_ws;
    __hip_bfloat16* Abf = (__hip_bfloat16*)(ws);
    __hip_bfloat16* Pbf = (__hip_bfloat16*)(ws + 1048576);
    float* a2c   = (float*)(ws + 2097152);
    float* pdc   = (float*)(ws + 2129920);
    float* p2g   = (float*)(ws + 2162688);
    int*   gic   = (int*)(ws + 2195456);
    int*   cnt   = (int*)(ws + 2228224);
    float* total = (float*)(ws + 2228228);

    hipMemsetAsync((void*)cnt, 0, 8, stream);

    prep_kernel<<<dim3(NROWS / 4), dim3(256), 0, stream>>>(A, P, labels, Abf, Pbf,
                                                           a2c, pdc, p2g, gic, cnt);

    dim3 grid(NROWS / 128, NROWS / 128);
    main_kernel<<<grid, dim3(256), 0, stream>>>(Abf, Pbf, a2c, pdc, p2g, gic, cnt, total);

    finalize_kernel<<<1, 1, 0, stream>>>(cnt, total, out);
}

// Round 3
// 107.381 us; speedup vs baseline: 2.2214x; 1.3749x over previous
//
#include <hip/hip_runtime.h>
#include <hip/hip_bf16.h>

#define NROWS 8192
#define DDIM 64
#define MARGIN_F 1.0f
#define EPS_F 1e-6f

// ws layout (bytes):
//  Abf  [0, 1 MB)          bf16[8192][64]  (a+eps), global row index
//  Pbf  [1 MB, 2 MB)       bf16[8192][64]
//  a2g  [2 MB, +32 KB)     float[8192]  |a+eps|^2
//  pdg  [+32 KB, +64 KB)   float[8192]  pos_dist + margin
//  p2g  [+64 KB, +96 KB)   float[8192]  |p|^2
//  sel  [+96 KB, +128 KB)  int[8192]    sorted indices of labels==1
//  cnt  at +128 KB (int)
//  total at +128 KB + 4 (float)

typedef __attribute__((ext_vector_type(8))) short bf16x8;
typedef __attribute__((ext_vector_type(4))) float f32x4;

__global__ __launch_bounds__(256) void
prep_kernel(const float* __restrict__ A, const float* __restrict__ P,
            __hip_bfloat16* __restrict__ Abf, __hip_bfloat16* __restrict__ Pbf,
            float* __restrict__ a2g, float* __restrict__ pdg,
            float* __restrict__ p2g) {
    int row  = blockIdx.x * 4 + (threadIdx.x >> 6);
    int lane = threadIdx.x & 63;
    float av = A[row * DDIM + lane] + EPS_F;
    float pv = P[row * DDIM + lane];
    Abf[row * DDIM + lane] = __float2bfloat16(av);
    Pbf[row * DDIM + lane] = __float2bfloat16(pv);
    float va2 = av * av;
    float vp2 = pv * pv;
    float vap = av * pv;
    #pragma unroll
    for (int off = 32; off; off >>= 1) {
        va2 += __shfl_xor(va2, off);
        vp2 += __shfl_xor(vp2, off);
        vap += __shfl_xor(vap, off);
    }
    if (lane == 0) {
        a2g[row] = va2;
        p2g[row] = vp2;
        float sq = fmaxf(va2 + vp2 - 2.0f * vap, 1e-12f);
        pdg[row] = sqrtf(sq) + MARGIN_F;
    }
}

// Deterministic compaction: no contended atomics. One block of 256 threads,
// each owning a contiguous 32-row chunk -> sel comes out sorted.
__global__ __launch_bounds__(256) void
compact_kernel(const int* __restrict__ labels, int* __restrict__ sel,
               int* __restrict__ cnt, float* __restrict__ total) {
    __shared__ int scan[256];
    int t = threadIdx.x;
    int lc = 0;
    #pragma unroll
    for (int i = 0; i < 32; ++i)
        lc += (labels[t * 32 + i] == 1) ? 1 : 0;
    scan[t] = lc;
    __syncthreads();
    #pragma unroll
    for (int off = 1; off < 256; off <<= 1) {
        int v = (t >= off) ? scan[t - off] : 0;
        __syncthreads();
        if (t >= off) scan[t] += v;
        __syncthreads();
    }
    int o = scan[t] - lc;  // exclusive base for this thread's chunk
    for (int i = 0; i < 32; ++i) {
        int r = t * 32 + i;
        if (labels[r] == 1) sel[o++] = r;
    }
    if (t == 255) *cnt = scan[255];
    if (t == 0)   *total = 0.0f;
}

#define LDS_STRIDE 72   // bf16 elements per row (144 B): 2-way bank aliasing only

__global__ __launch_bounds__(256) void
main_kernel(const __hip_bfloat16* __restrict__ Abf, const __hip_bfloat16* __restrict__ Pbf,
            const float* __restrict__ a2g, const float* __restrict__ pdg,
            const float* __restrict__ p2g, const int* __restrict__ sel,
            const int* __restrict__ cnt, float* __restrict__ total) {
    __shared__ __align__(16) unsigned short As[128 * LDS_STRIDE];
    __shared__ __align__(16) unsigned short Ps2[128 * LDS_STRIDE];
    __shared__ float sA2[128], sPd[128], sP2[128];
    __shared__ int   sGi[128];
    __shared__ float wsum[4];

    int M = *cnt;
    int row0 = blockIdx.y * 128;   // position in compacted list
    int col0 = blockIdx.x * 128;   // global positive index
    if (row0 >= M) return;

    int t = threadIdx.x;

    if (t < 128) {
        int gi = sel[min(row0 + t, M - 1)];
        sGi[t] = gi;
        sA2[t] = a2g[gi];
        sPd[t] = pdg[gi];
        sP2[t] = p2g[col0 + t];
    }
    __syncthreads();

    // Stage tiles: 128 rows x 64 bf16 (8 chunks of 16B per row), padded stride.
    const float4* Asrc = (const float4*)Abf;
    const float4* Psrc = (const float4*)Pbf;
    #pragma unroll
    for (int i = 0; i < 4; ++i) {
        int c  = t + i * 256;      // 0..1023
        int r  = c >> 3;
        int kc = c & 7;
        int ar = sGi[r];
        *(float4*)&As[r * LDS_STRIDE + kc * 8]  = Asrc[ar * 8 + kc];
        *(float4*)&Ps2[r * LDS_STRIDE + kc * 8] = Psrc[(col0 + r) * 8 + kc];
    }
    __syncthreads();

    int wid  = t >> 6;
    int lane = t & 63;
    int wm = (wid >> 1) * 64;      // wave's 64x64 sub-tile
    int wn = (wid & 1) * 64;
    int lm   = lane & 15;
    int quad = lane >> 4;

    f32x4 acc[4][4] = {};
    #pragma unroll
    for (int s = 0; s < 2; ++s) {
        bf16x8 af[4], bfr[4];
        #pragma unroll
        for (int a = 0; a < 4; ++a)
            af[a] = *(const bf16x8*)&As[(wm + a * 16 + lm) * LDS_STRIDE + s * 32 + quad * 8];
        #pragma unroll
        for (int b = 0; b < 4; ++b)
            bfr[b] = *(const bf16x8*)&Ps2[(wn + b * 16 + lm) * LDS_STRIDE + s * 32 + quad * 8];
        #pragma unroll
        for (int a = 0; a < 4; ++a)
            #pragma unroll
            for (int b = 0; b < 4; ++b)
                acc[a][b] = __builtin_amdgcn_mfma_f32_16x16x32_bf16(af[a], bfr[b], acc[a][b], 0, 0, 0);
    }

    // Fused epilogue. C/D layout: col = lane&15, row = quad*4 + reg.
    float bsum = 0.0f;
    #pragma unroll
    for (int a = 0; a < 4; ++a) {
        #pragma unroll
        for (int r = 0; r < 4; ++r) {
            int il = wm + a * 16 + quad * 4 + r;
            bool valid = (row0 + il) < M;
            float ra2 = sA2[il];
            float rpd = sPd[il];
            int   gi  = sGi[il];
            #pragma unroll
            for (int b = 0; b < 4; ++b) {
                int jl = wn + b * 16 + lm;
                int j  = col0 + jl;
                float sq = fmaxf(ra2 + sP2[jl] - 2.0f * acc[a][b][r], 1e-12f);
                float h  = rpd - sqrtf(sq);
                if (valid && (gi != j) && (h > 0.0f)) bsum += h;
            }
        }
    }

    #pragma unroll
    for (int off = 32; off; off >>= 1) bsum += __shfl_xor(bsum, off);
    if (lane == 0) wsum[wid] = bsum;
    __syncthreads();
    if (t == 0) atomicAdd(total, wsum[0] + wsum[1] + wsum[2] + wsum[3]);
}

__global__ void finalize_kernel(const int* __restrict__ cnt,
                                const float* __restrict__ total,
                                float* __restrict__ out) {
    int M = *cnt;
    float c = (float)M * (float)(NROWS - 1);
    out[0] = (M > 0) ? (*total) / c : 0.0f;
}

extern "C" void kernel_launch(void* const* d_in, const int* in_sizes, int n_in,
                              void* d_out, int out_size, void* d_ws, size_t ws_size,
                              hipStream_t stream) {
    const float* A      = (const float*)d_in[0];
    const float* P      = (const float*)d_in[1];
    const int*   labels = (const int*)d_in[2];
    float* out = (float*)d_out;

    char* ws = (char*)d_ws;
    __hip_bfloat16* Abf = (__hip_bfloat16*)(ws);
    __hip_bfloat16* Pbf = (__hip_bfloat16*)(ws + (1 << 20));
    float* a2g   = (float*)(ws + (2 << 20));
    float* pdg   = (float*)(ws + (2 << 20) + 32768);
    float* p2g   = (float*)(ws + (2 << 20) + 65536);
    int*   sel   = (int*)(ws + (2 << 20) + 98304);
    int*   cnt   = (int*)(ws + (2 << 20) + 131072);
    float* total = (float*)(ws + (2 << 20) + 131076);

    prep_kernel<<<dim3(NROWS / 4), dim3(256), 0, stream>>>(A, P, Abf, Pbf, a2g, pdg, p2g);
    compact_kernel<<<dim3(1), dim3(256), 0, stream>>>(labels, sel, cnt, total);

    dim3 grid(NROWS / 128, NROWS / 128);
    main_kernel<<<grid, dim3(256), 0, stream>>>(Abf, Pbf, a2g, pdg, p2g, sel, cnt, total);

    finalize_kernel<<<1, 1, 0, stream>>>(cnt, total, out);
}

// Round 4
// 96.605 us; speedup vs baseline: 2.4692x; 1.1116x over previous
//
#include <hip/hip_runtime.h>
#include <hip/hip_bf16.h>

#define NROWS 8192
#define DDIM 64
#define MARGIN_F 1.0f
#define EPS_F 1e-6f

// ws layout (bytes):
//  Abf  [0, 1 MB)          bf16[8192][64]  (a+eps)
//  Pbf  [1 MB, 2 MB)       bf16[8192][64]
//  a2g  [2 MB, +32 KB)     float[8192]  |a+eps|^2
//  pdg  [+32 KB, +64 KB)   float[8192]  pos_dist + margin
//  p2g  [+64 KB, +96 KB)   float[8192]  |p|^2
//  sel  [+96 KB, +128 KB)  int[8192]    sorted indices of labels==1
//  cnt  at +128 KB (int)
//  partial [+132 KB, +148 KB)  float[4096]  per-block partial sums

typedef __attribute__((ext_vector_type(8))) short bf16x8;
typedef __attribute__((ext_vector_type(4))) float f32x4;

static __device__ __forceinline__ unsigned short f2bf(float x) {
    __hip_bfloat16 h = __float2bfloat16(x);
    return *reinterpret_cast<unsigned short*>(&h);
}

// Each thread: 4 consecutive cols of one row (float4 load, ushort4 store).
__global__ __launch_bounds__(256) void
prep_kernel(const float* __restrict__ A, const float* __restrict__ P,
            unsigned short* __restrict__ Abf, unsigned short* __restrict__ Pbf,
            float* __restrict__ a2g, float* __restrict__ pdg,
            float* __restrict__ p2g) {
    int t   = threadIdx.x;
    int gid = blockIdx.x * 256 + t;
    int row = gid >> 4;
    int c4  = (gid & 15) * 4;
    float4 a = *(const float4*)&A[row * DDIM + c4];
    float4 p = *(const float4*)&P[row * DDIM + c4];
    a.x += EPS_F; a.y += EPS_F; a.z += EPS_F; a.w += EPS_F;
    ushort4 ab, pb;
    ab.x = f2bf(a.x); ab.y = f2bf(a.y); ab.z = f2bf(a.z); ab.w = f2bf(a.w);
    pb.x = f2bf(p.x); pb.y = f2bf(p.y); pb.z = f2bf(p.z); pb.w = f2bf(p.w);
    *(ushort4*)&Abf[row * DDIM + c4] = ab;
    *(ushort4*)&Pbf[row * DDIM + c4] = pb;
    float va2 = a.x*a.x + a.y*a.y + a.z*a.z + a.w*a.w;
    float vp2 = p.x*p.x + p.y*p.y + p.z*p.z + p.w*p.w;
    float vap = a.x*p.x + a.y*p.y + a.z*p.z + a.w*p.w;
    #pragma unroll
    for (int off = 8; off; off >>= 1) {
        va2 += __shfl_xor(va2, off);
        vp2 += __shfl_xor(vp2, off);
        vap += __shfl_xor(vap, off);
    }
    if ((t & 15) == 0) {
        a2g[row] = va2;
        p2g[row] = vp2;
        float sq = fmaxf(va2 + vp2 - 2.0f * vap, 1e-12f);
        pdg[row] = sqrtf(sq) + MARGIN_F;
    }
}

// Deterministic compaction, one block. Labels staged to LDS coalesced; chunk
// layout padded (33-stride) so per-thread chunk reads are conflict-free.
__global__ __launch_bounds__(256) void
compact_kernel(const int* __restrict__ labels, int* __restrict__ sel,
               int* __restrict__ cnt) {
    __shared__ int lab[256 * 33];
    __shared__ int scan[256];
    int t = threadIdx.x;
    #pragma unroll
    for (int i = 0; i < 32; ++i) {
        int j = i * 256 + t;                 // coalesced global read
        lab[(j >> 5) * 33 + (j & 31)] = labels[j];
    }
    __syncthreads();
    int lc = 0;
    #pragma unroll
    for (int i = 0; i < 32; ++i) lc += (lab[t * 33 + i] == 1) ? 1 : 0;
    scan[t] = lc;
    __syncthreads();
    for (int off = 1; off < 256; off <<= 1) {
        int v = (t >= off) ? scan[t - off] : 0;
        __syncthreads();
        if (t >= off) scan[t] += v;
        __syncthreads();
    }
    int o = scan[t] - lc;
    for (int i = 0; i < 32; ++i) {
        if (lab[t * 33 + i] == 1) sel[o++] = t * 32 + i;
    }
    if (t == 255) *cnt = scan[255];
}

// 128x128 tile per block, 4 waves of 64x64. MFMA fragments loaded DIRECTLY
// from global (L2-resident) -> no LDS data path, no staging barriers.
__global__ __launch_bounds__(256) void
main_kernel(const unsigned short* __restrict__ Abf, const unsigned short* __restrict__ Pbf,
            const float* __restrict__ a2g, const float* __restrict__ pdg,
            const float* __restrict__ p2g, const int* __restrict__ sel,
            const int* __restrict__ cnt, float* __restrict__ partial) {
    __shared__ float sA2[128], sPd[128], sP2[128];
    __shared__ int   sGi[128];
    __shared__ float wsum[4];

    int M = *cnt;
    int row0 = blockIdx.y * 128;   // position in compacted list
    int col0 = blockIdx.x * 128;   // global positive index
    int bid  = blockIdx.y * 64 + blockIdx.x;
    int t = threadIdx.x;
    if (row0 >= M) { if (t == 0) partial[bid] = 0.0f; return; }

    if (t < 128) {
        int gi = sel[min(row0 + t, M - 1)];
        sGi[t] = gi;
        sA2[t] = a2g[gi];
        sPd[t] = pdg[gi];
        sP2[t] = p2g[col0 + t];
    }
    __syncthreads();

    int wid  = t >> 6;
    int lane = t & 63;
    int wm = (wid >> 1) * 64;      // wave's 64x64 sub-tile
    int wn = (wid & 1) * 64;
    int lm   = lane & 15;
    int quad = lane >> 4;

    // A fragment: lane holds A[m=lm][k=quad*8..+8] of its 16-row group.
    bf16x8 af[2][4], bg[2][4];
    #pragma unroll
    for (int a = 0; a < 4; ++a) {
        const unsigned short* pa = Abf + (size_t)sGi[wm + a * 16 + lm] * DDIM + quad * 8;
        af[0][a] = *(const bf16x8*)pa;
        af[1][a] = *(const bf16x8*)(pa + 32);
    }
    #pragma unroll
    for (int b = 0; b < 4; ++b) {
        const unsigned short* pb = Pbf + (size_t)(col0 + wn + b * 16 + lm) * DDIM + quad * 8;
        bg[0][b] = *(const bf16x8*)pb;
        bg[1][b] = *(const bf16x8*)(pb + 32);
    }

    f32x4 acc[4][4] = {};
    #pragma unroll
    for (int s = 0; s < 2; ++s)
        #pragma unroll
        for (int a = 0; a < 4; ++a)
            #pragma unroll
            for (int b = 0; b < 4; ++b)
                acc[a][b] = __builtin_amdgcn_mfma_f32_16x16x32_bf16(af[s][a], bg[s][b], acc[a][b], 0, 0, 0);

    // Fused epilogue. C/D layout: col = lane&15, row = quad*4 + reg.
    float bsum = 0.0f;
    #pragma unroll
    for (int a = 0; a < 4; ++a) {
        #pragma unroll
        for (int r = 0; r < 4; ++r) {
            int il = wm + a * 16 + quad * 4 + r;
            bool valid = (row0 + il) < M;
            float ra2 = sA2[il];
            float rpd = sPd[il];
            int   gi  = sGi[il];
            #pragma unroll
            for (int b = 0; b < 4; ++b) {
                int jl = wn + b * 16 + lm;
                int j  = col0 + jl;
                float sq = fmaxf(ra2 + sP2[jl] - 2.0f * acc[a][b][r], 1e-12f);
                float h  = rpd - sqrtf(sq);
                if (valid && (gi != j) && (h > 0.0f)) bsum += h;
            }
        }
    }

    #pragma unroll
    for (int off = 32; off; off >>= 1) bsum += __shfl_xor(bsum, off);
    if (lane == 0) wsum[wid] = bsum;
    __syncthreads();
    if (t == 0) partial[bid] = wsum[0] + wsum[1] + wsum[2] + wsum[3];  // no atomics
}

__global__ __launch_bounds__(256) void
finalize_kernel(const int* __restrict__ cnt, const float* __restrict__ partial,
                float* __restrict__ out) {
    __shared__ float wsum[4];
    int t = threadIdx.x;
    const float4* p4 = (const float4*)partial;
    float s = 0.0f;
    #pragma unroll
    for (int i = 0; i < 4; ++i) {
        float4 v = p4[i * 256 + t];
        s += v.x + v.y + v.z + v.w;
    }
    #pragma unroll
    for (int off = 32; off; off >>= 1) s += __shfl_xor(s, off);
    if ((t & 63) == 0) wsum[t >> 6] = s;
    __syncthreads();
    if (t == 0) {
        int M = *cnt;
        float tot = wsum[0] + wsum[1] + wsum[2] + wsum[3];
        float c = (float)M * (float)(NROWS - 1);
        out[0] = (M > 0) ? tot / c : 0.0f;
    }
}

extern "C" void kernel_launch(void* const* d_in, const int* in_sizes, int n_in,
                              void* d_out, int out_size, void* d_ws, size_t ws_size,
                              hipStream_t stream) {
    const float* A      = (const float*)d_in[0];
    const float* P      = (const float*)d_in[1];
    const int*   labels = (const int*)d_in[2];
    float* out = (float*)d_out;

    char* ws = (char*)d_ws;
    unsigned short* Abf = (unsigned short*)(ws);
    unsigned short* Pbf = (unsigned short*)(ws + (1 << 20));
    float* a2g     = (float*)(ws + (2 << 20));
    float* pdg     = (float*)(ws + (2 << 20) + 32768);
    float* p2g     = (float*)(ws + (2 << 20) + 65536);
    int*   sel     = (int*)(ws + (2 << 20) + 98304);
    int*   cnt     = (int*)(ws + (2 << 20) + 131072);
    float* partial = (float*)(ws + (2 << 20) + 135168);

    prep_kernel<<<dim3(NROWS * 16 / 256), dim3(256), 0, stream>>>(A, P, Abf, Pbf, a2g, pdg, p2g);
    compact_kernel<<<dim3(1), dim3(256), 0, stream>>>(labels, sel, cnt);

    dim3 grid(NROWS / 128, NROWS / 128);
    main_kernel<<<grid, dim3(256), 0, stream>>>(Abf, Pbf, a2g, pdg, p2g, sel, cnt, partial);

    finalize_kernel<<<1, dim3(256), 0, stream>>>(cnt, partial, out);
}

// Round 5
// 89.959 us; speedup vs baseline: 2.6516x; 1.0739x over previous
//
#include <hip/hip_runtime.h>
#include <hip/hip_bf16.h>

#define NROWS 8192
#define DDIM 64
#define MARGIN_F 1.0f
#define EPS_F 1e-6f

// ws layout (bytes), base 2 MB region after Abf/Pbf:
//  Abf  [0, 1 MB)            bf16[8192][64]  (a+eps)
//  Pbf  [1 MB, 2 MB)         bf16[8192][64]
//  a2g  +0      float[8192]  |a+eps|^2 (fp32 exact)
//  pdg  +32 KB  float[8192]  pos_dist + margin (fp32 exact)
//  p2g  +64 KB  float[8192]  |p|^2
//  sel  +96 KB  int[8192]    sorted indices of labels==1
//  cnt  +128 KB (int)
//  partial +132 KB float[4096] per-block partial sums
//  hdg  +148 KB float[8192]  diag hinge per row (bf16-gram), to subtract

typedef __attribute__((ext_vector_type(8))) short bf16x8;
typedef __attribute__((ext_vector_type(4))) float f32x4;

static __device__ __forceinline__ unsigned short f2bf(float x) {
    __hip_bfloat16 h = __float2bfloat16(x);
    return *reinterpret_cast<unsigned short*>(&h);
}
static __device__ __forceinline__ float bf2f(unsigned short u) {
    return __uint_as_float(((unsigned)u) << 16);
}

// Fused prep (blocks 0..511) + compaction (block 512).
__global__ __launch_bounds__(256) void
prep_compact_kernel(const float* __restrict__ A, const float* __restrict__ P,
                    const int* __restrict__ labels,
                    unsigned short* __restrict__ Abf, unsigned short* __restrict__ Pbf,
                    float* __restrict__ a2g, float* __restrict__ pdg,
                    float* __restrict__ p2g, float* __restrict__ hdg,
                    int* __restrict__ sel, int* __restrict__ cnt) {
    __shared__ int lab[256 * 33];   // only used by block 512
    __shared__ int scan[256];
    int t = threadIdx.x;

    if (blockIdx.x < 512) {
        // prep: 16 threads per row, 4 cols each
        int gid = blockIdx.x * 256 + t;
        int row = gid >> 4;
        int c4  = (gid & 15) * 4;
        float4 a = *(const float4*)&A[row * DDIM + c4];
        float4 p = *(const float4*)&P[row * DDIM + c4];
        a.x += EPS_F; a.y += EPS_F; a.z += EPS_F; a.w += EPS_F;
        ushort4 ab, pb;
        ab.x = f2bf(a.x); ab.y = f2bf(a.y); ab.z = f2bf(a.z); ab.w = f2bf(a.w);
        pb.x = f2bf(p.x); pb.y = f2bf(p.y); pb.z = f2bf(p.z); pb.w = f2bf(p.w);
        *(ushort4*)&Abf[row * DDIM + c4] = ab;
        *(ushort4*)&Pbf[row * DDIM + c4] = pb;
        float va2 = a.x*a.x + a.y*a.y + a.z*a.z + a.w*a.w;
        float vp2 = p.x*p.x + p.y*p.y + p.z*p.z + p.w*p.w;
        float vap = a.x*p.x + a.y*p.y + a.z*p.z + a.w*p.w;
        // bf16-rounded diag dot (must match what main's MFMA adds for (i,i))
        float vdd = bf2f(ab.x)*bf2f(pb.x) + bf2f(ab.y)*bf2f(pb.y)
                  + bf2f(ab.z)*bf2f(pb.z) + bf2f(ab.w)*bf2f(pb.w);
        #pragma unroll
        for (int off = 8; off; off >>= 1) {
            va2 += __shfl_xor(va2, off);
            vp2 += __shfl_xor(vp2, off);
            vap += __shfl_xor(vap, off);
            vdd += __shfl_xor(vdd, off);
        }
        if ((t & 15) == 0) {
            a2g[row] = va2;
            p2g[row] = vp2;
            float pd = sqrtf(fmaxf(va2 + vp2 - 2.0f * vap, 1e-12f)) + MARGIN_F;
            pdg[row] = pd;
            float sqd = fmaxf(va2 + vp2 - 2.0f * vdd, 1e-12f);
            hdg[row] = fmaxf(pd - __builtin_amdgcn_sqrtf(sqd), 0.0f);
        }
    } else {
        // compaction: deterministic, sorted, no atomics
        #pragma unroll
        for (int i = 0; i < 32; ++i) {
            int j = i * 256 + t;                 // coalesced global read
            lab[(j >> 5) * 33 + (j & 31)] = labels[j];
        }
        __syncthreads();
        int lc = 0;
        #pragma unroll
        for (int i = 0; i < 32; ++i) lc += (lab[t * 33 + i] == 1) ? 1 : 0;
        scan[t] = lc;
        __syncthreads();
        for (int off = 1; off < 256; off <<= 1) {
            int v = (t >= off) ? scan[t - off] : 0;
            __syncthreads();
            if (t >= off) scan[t] += v;
            __syncthreads();
        }
        int o = scan[t] - lc;
        for (int i = 0; i < 32; ++i) {
            if (lab[t * 33 + i] == 1) sel[o++] = t * 32 + i;
        }
        if (t == 255) *cnt = scan[255];
    }
}

// 128x128 tile per block, 4 waves of 64x64, fragments direct from L2.
// Accumulates ALL columns (diag included; subtracted in finalize).
__global__ __launch_bounds__(256) void
main_kernel(const unsigned short* __restrict__ Abf, const unsigned short* __restrict__ Pbf,
            const float* __restrict__ a2g, const float* __restrict__ pdg,
            const float* __restrict__ p2g, const int* __restrict__ sel,
            const int* __restrict__ cnt, float* __restrict__ partial) {
    __shared__ float sA2[128], sPd[128], sP2[128];
    __shared__ int   sGi[128];
    __shared__ float wsum[4];

    int M = *cnt;
    int row0 = blockIdx.y << 7;
    int col0 = blockIdx.x << 7;
    int bid  = (blockIdx.y << 6) + blockIdx.x;
    int t = threadIdx.x;
    if (row0 >= M) { if (t == 0) partial[bid] = 0.0f; return; }

    int wid  = t >> 6;
    int lane = t & 63;
    int wm   = (wid >> 1) << 6;
    int wn   = (wid & 1) << 6;
    int lm   = lane & 15;
    int quad = lane >> 4;

    // B fragments first (no dependence on sel): loads in flight across barrier.
    bf16x8 bg[2][4];
    #pragma unroll
    for (int b = 0; b < 4; ++b) {
        const unsigned short* pb = Pbf + (size_t)(col0 + wn + b * 16 + lm) * DDIM + quad * 8;
        bg[0][b] = *(const bf16x8*)pb;
        bg[1][b] = *(const bf16x8*)(pb + 32);
    }

    if (t < 128) {
        int gi = sel[min(row0 + t, M - 1)];
        sGi[t] = gi;
        sA2[t] = a2g[gi];
        sPd[t] = pdg[gi];
        sP2[t] = p2g[col0 + t];
    }
    __syncthreads();

    bf16x8 af[2][4];
    #pragma unroll
    for (int a = 0; a < 4; ++a) {
        const unsigned short* pa = Abf + (size_t)sGi[wm + a * 16 + lm] * DDIM + quad * 8;
        af[0][a] = *(const bf16x8*)pa;
        af[1][a] = *(const bf16x8*)(pa + 32);
    }

    f32x4 acc[4][4] = {};
    #pragma unroll
    for (int s = 0; s < 2; ++s)
        #pragma unroll
        for (int a = 0; a < 4; ++a)
            #pragma unroll
            for (int b = 0; b < 4; ++b)
                acc[a][b] = __builtin_amdgcn_mfma_f32_16x16x32_bf16(af[s][a], bg[s][b], acc[a][b], 0, 0, 0);

    // Branchless epilogue. C/D layout: col = lane&15, row = quad*4 + reg.
    // sq = a2+p2-2*dot >= ~50 for D=64 gaussians -> no clamp needed, raw v_sqrt.
    float spv[4];
    #pragma unroll
    for (int b = 0; b < 4; ++b) spv[b] = sP2[wn + b * 16 + lm];

    float bsum = 0.0f;
    #pragma unroll
    for (int a = 0; a < 4; ++a) {
        #pragma unroll
        for (int r = 0; r < 4; ++r) {
            int il = wm + a * 16 + quad * 4 + r;
            float rm  = ((row0 + il) < M) ? 1.0f : 0.0f;   // validity, folded into fmac
            float ra2 = sA2[il];
            float rpd = sPd[il];
            #pragma unroll
            for (int b = 0; b < 4; ++b) {
                float sq = fmaf(-2.0f, acc[a][b][r], ra2 + spv[b]);
                float h  = rpd - __builtin_amdgcn_sqrtf(sq);
                bsum = fmaf(fmaxf(h, 0.0f), rm, bsum);
            }
        }
    }

    #pragma unroll
    for (int off = 32; off; off >>= 1) bsum += __shfl_xor(bsum, off);
    if (lane == 0) wsum[wid] = bsum;
    __syncthreads();
    if (t == 0) partial[bid] = wsum[0] + wsum[1] + wsum[2] + wsum[3];
}

__global__ __launch_bounds__(256) void
finalize_kernel(const int* __restrict__ cnt, const float* __restrict__ partial,
                const float* __restrict__ hdg, const int* __restrict__ sel,
                float* __restrict__ out) {
    __shared__ float wsum[4];
    int t = threadIdx.x;
    const float4* p4 = (const float4*)partial;
    float s = 0.0f;
    #pragma unroll
    for (int i = 0; i < 4; ++i) {
        float4 v = p4[i * 256 + t];
        s += v.x + v.y + v.z + v.w;
    }
    int M = *cnt;
    for (int idx = t; idx < M; idx += 256) s -= hdg[sel[idx]];   // remove diagonals
    #pragma unroll
    for (int off = 32; off; off >>= 1) s += __shfl_xor(s, off);
    if ((t & 63) == 0) wsum[t >> 6] = s;
    __syncthreads();
    if (t == 0) {
        float tot = wsum[0] + wsum[1] + wsum[2] + wsum[3];
        float c = (float)M * (float)(NROWS - 1);
        out[0] = (M > 0) ? tot / c : 0.0f;
    }
}

extern "C" void kernel_launch(void* const* d_in, const int* in_sizes, int n_in,
                              void* d_out, int out_size, void* d_ws, size_t ws_size,
                              hipStream_t stream) {
    const float* A      = (const float*)d_in[0];
    const float* P      = (const float*)d_in[1];
    const int*   labels = (const int*)d_in[2];
    float* out = (float*)d_out;

    char* ws = (char*)d_ws;
    unsigned short* Abf = (unsigned short*)(ws);
    unsigned short* Pbf = (unsigned short*)(ws + (1 << 20));
    float* a2g     = (float*)(ws + (2 << 20));
    float* pdg     = (float*)(ws + (2 << 20) + 32768);
    float* p2g     = (float*)(ws + (2 << 20) + 65536);
    int*   sel     = (int*)(ws + (2 << 20) + 98304);
    int*   cnt     = (int*)(ws + (2 << 20) + 131072);
    float* partial = (float*)(ws + (2 << 20) + 135168);
    float* hdg     = (float*)(ws + (2 << 20) + 151552);

    prep_compact_kernel<<<dim3(513), dim3(256), 0, stream>>>(A, P, labels, Abf, Pbf,
                                                             a2g, pdg, p2g, hdg, sel, cnt);

    dim3 grid(NROWS / 128, NROWS / 128);
    main_kernel<<<grid, dim3(256), 0, stream>>>(Abf, Pbf, a2g, pdg, p2g, sel, cnt, partial);

    finalize_kernel<<<1, dim3(256), 0, stream>>>(cnt, partial, hdg, sel, out);
}